// Round 1
// baseline (576.113 us; speedup 1.0000x reference)
//
#include <hip/hip_runtime.h>
#include <hip/hip_bf16.h>

// BasicCae: x[256,28224] fp32, W_enc[1500,28224], b_enc[1500], W_dec[28224,1500], b_dec[28224]
// out: y_out[256,28224] fp32 ++ jac_reg scalar (at index 7225344)

#define BATCH 256
#define IN    28224
#define FEAT  1500

typedef __attribute__((ext_vector_type(8))) short short8;   // 8 bf16 (4 VGPRs)
typedef __attribute__((ext_vector_type(4))) float f32x4;    // MFMA acc

__device__ __forceinline__ unsigned short f2bf(float f) {
    unsigned int u = __float_as_uint(f);
    u = (u + 0x7FFFu + ((u >> 16) & 1u)) >> 16;   // RNE
    return (unsigned short)u;
}

// ---------------- Encoder: preact[b,f] += x[b, k0:k1] . W_enc[f, k0:k1] -------------
// BM=256 (full batch), BN=64, BK=32, 4 waves each computing 64x64.
// grid = (24 N-tiles, 21 K-splits). Also accumulates row_norm2 (exact fp32) while
// staging W_enc (each W_enc element visited exactly once across the grid).
#define ENC_KCH 1344   /* 28224/21, = 42*32 */

__global__ __launch_bounds__(256) void enc_gemm(const float* __restrict__ x,
                                                const float* __restrict__ We,
                                                float* __restrict__ preact,
                                                float* __restrict__ rn2) {
    const int n0 = blockIdx.x * 64;
    const int kbase = blockIdx.y * ENC_KCH;

    __shared__ unsigned short As[256 * 40];   // 256 x (32+8 pad) bf16
    __shared__ unsigned short Bs[64 * 40];
    __shared__ float rowsq[64];

    const int t    = threadIdx.x;
    const int lane = t & 63;
    const int w    = t >> 6;        // wave 0..3 -> rows [w*64, w*64+64)
    const int l15  = lane & 15;
    const int quad = lane >> 4;

    if (t < 64) rowsq[t] = 0.0f;
    __syncthreads();

    f32x4 acc[4][4];
#pragma unroll
    for (int mt = 0; mt < 4; ++mt)
#pragma unroll
        for (int nt = 0; nt < 4; ++nt) { f32x4 z = {0.f, 0.f, 0.f, 0.f}; acc[mt][nt] = z; }

    for (int kt = 0; kt < ENC_KCH / 32; ++kt) {
        const int k0 = kbase + kt * 32;
        // stage A (x): 256x32 fp32 = 2048 float4, 8 per thread
#pragma unroll
        for (int j = 0; j < 8; ++j) {
            int idx = t + 256 * j;
            int row = idx >> 3;          // 0..255
            int c4  = idx & 7;           // float4 within row
            const float4 v = *(const float4*)(x + row * IN + k0 + c4 * 4);
            ushort4 h;
            h.x = f2bf(v.x); h.y = f2bf(v.y); h.z = f2bf(v.z); h.w = f2bf(v.w);
            *(ushort4*)&As[row * 40 + c4 * 4] = h;
        }
        // stage B (W_enc): 64x32 fp32 = 512 float4, 2 per thread; fused sum-of-squares
#pragma unroll
        for (int j = 0; j < 2; ++j) {
            int idx = t + 256 * j;
            int row = idx >> 3;          // 0..63
            int c4  = idx & 7;
            int f   = n0 + row;
            float4 v = make_float4(0.f, 0.f, 0.f, 0.f);
            if (f < FEAT) v = *(const float4*)(We + (long)f * IN + k0 + c4 * 4);
            ushort4 h;
            h.x = f2bf(v.x); h.y = f2bf(v.y); h.z = f2bf(v.z); h.w = f2bf(v.w);
            *(ushort4*)&Bs[row * 40 + c4 * 4] = h;
            float sq = v.x * v.x + v.y * v.y + v.z * v.z + v.w * v.w;
            atomicAdd(&rowsq[row], sq);
        }
        __syncthreads();

        short8 a[4], b[4];
#pragma unroll
        for (int mt = 0; mt < 4; ++mt)
            a[mt] = *(const short8*)&As[(w * 64 + mt * 16 + l15) * 40 + quad * 8];
#pragma unroll
        for (int nt = 0; nt < 4; ++nt)
            b[nt] = *(const short8*)&Bs[(nt * 16 + l15) * 40 + quad * 8];
#pragma unroll
        for (int mt = 0; mt < 4; ++mt)
#pragma unroll
            for (int nt = 0; nt < 4; ++nt)
                acc[mt][nt] = __builtin_amdgcn_mfma_f32_16x16x32_bf16(a[mt], b[nt], acc[mt][nt], 0, 0, 0);
        __syncthreads();
    }

    // split-K partials -> fp32 atomics (device scope)
#pragma unroll
    for (int mt = 0; mt < 4; ++mt) {
#pragma unroll
        for (int nt = 0; nt < 4; ++nt) {
            int col = n0 + nt * 16 + l15;
            if (col < FEAT) {
#pragma unroll
                for (int r = 0; r < 4; ++r) {
                    int row = w * 64 + mt * 16 + quad * 4 + r;
                    atomicAdd(&preact[row * FEAT + col], acc[mt][nt][r]);
                }
            }
        }
    }

    // flush row_norm2 partials (all LDS atomics completed before last loop barrier)
    if (t < 64) {
        int f = n0 + t;
        if (f < FEAT) atomicAdd(&rn2[f], rowsq[t]);
    }
}

// ---------------- Activation + Jacobian regularizer ----------------
// grid = (6, 256): blockIdx.y = batch row, covers padded F=1536 cols.
__global__ __launch_bounds__(256) void act_jac(const float* __restrict__ preact,
                                               const float* __restrict__ be,
                                               const float* __restrict__ rn2,
                                               unsigned short* __restrict__ yenc,
                                               float* __restrict__ jac) {
    const int b = blockIdx.y;
    const int f = blockIdx.x * 256 + threadIdx.x;   // 0..1535
    float local = 0.0f;
    unsigned short h = 0;
    if (f < FEAT) {
        float p = preact[b * FEAT + f] + be[f];
        float y = 1.0f / (1.0f + __expf(-p));
        h = f2bf(y);
        float s = y * (1.0f - y);
        local = s * s * rn2[f];
    }
    yenc[b * 1536 + f] = h;   // zero-pads cols 1500..1535

    // block reduction
    float v = local;
#pragma unroll
    for (int off = 32; off > 0; off >>= 1) v += __shfl_down(v, off);
    __shared__ float red[4];
    const int lane = threadIdx.x & 63;
    const int w = threadIdx.x >> 6;
    if (lane == 0) red[w] = v;
    __syncthreads();
    if (threadIdx.x == 0) atomicAdd(jac, red[0] + red[1] + red[2] + red[3]);
}

// ---------------- Decoder: out[b,i] = sigmoid(yenc[b,:] . W_dec[i,:] + b_dec[i]) ----
// BM=256, BN=64, BK=32, 4 waves; grid = 441 N-tiles (28224/64 exact). K padded 1536.
__global__ __launch_bounds__(256) void dec_gemm(const unsigned short* __restrict__ yenc,
                                                const float* __restrict__ Wd,
                                                const float* __restrict__ bd,
                                                float* __restrict__ out) {
    const int n0 = blockIdx.x * 64;

    __shared__ unsigned short As[256 * 40];
    __shared__ unsigned short Bs[64 * 40];

    const int t    = threadIdx.x;
    const int lane = t & 63;
    const int w    = t >> 6;
    const int l15  = lane & 15;
    const int quad = lane >> 4;

    f32x4 acc[4][4];
#pragma unroll
    for (int mt = 0; mt < 4; ++mt)
#pragma unroll
        for (int nt = 0; nt < 4; ++nt) { f32x4 z = {0.f, 0.f, 0.f, 0.f}; acc[mt][nt] = z; }

    for (int kt = 0; kt < 48; ++kt) {   // 48*32 = 1536
        const int k0 = kt * 32;
        // stage A (yenc, already bf16): 256x32 = 1024 chunks of 8 bf16, 4 per thread
#pragma unroll
        for (int j = 0; j < 4; ++j) {
            int idx = t + 256 * j;
            int row = idx >> 2;          // 0..255
            int c   = idx & 3;           // chunk of 8 bf16
            const short8 v = *(const short8*)(yenc + row * 1536 + k0 + c * 8);
            *(short8*)&As[row * 40 + c * 8] = v;
        }
        // stage B (W_dec fp32 -> bf16): 64x32 = 512 float4, 2 per thread; K-guard
#pragma unroll
        for (int j = 0; j < 2; ++j) {
            int idx = t + 256 * j;
            int row = idx >> 3;          // 0..63
            int c4  = idx & 7;
            int i   = n0 + row;          // always < 28224
            int k   = k0 + c4 * 4;
            float4 v = make_float4(0.f, 0.f, 0.f, 0.f);
            if (k < 1500) v = *(const float4*)(Wd + (long)i * FEAT + k);
            ushort4 h;
            h.x = f2bf(v.x); h.y = f2bf(v.y); h.z = f2bf(v.z); h.w = f2bf(v.w);
            *(ushort4*)&Bs[row * 40 + c4 * 4] = h;
        }
        __syncthreads();

        short8 a[4], b[4];
#pragma unroll
        for (int mt = 0; mt < 4; ++mt)
            a[mt] = *(const short8*)&As[(w * 64 + mt * 16 + l15) * 40 + quad * 8];
#pragma unroll
        for (int nt = 0; nt < 4; ++nt)
            b[nt] = *(const short8*)&Bs[(nt * 16 + l15) * 40 + quad * 8];
#pragma unroll
        for (int mt = 0; mt < 4; ++mt)
#pragma unroll
            for (int nt = 0; nt < 4; ++nt)
                acc[mt][nt] = __builtin_amdgcn_mfma_f32_16x16x32_bf16(a[mt], b[nt], acc[mt][nt], 0, 0, 0);
        __syncthreads();
    }

    // epilogue: bias + sigmoid, direct store
#pragma unroll
    for (int mt = 0; mt < 4; ++mt) {
#pragma unroll
        for (int nt = 0; nt < 4; ++nt) {
            int col = n0 + nt * 16 + l15;
            float bias = bd[col];
#pragma unroll
            for (int r = 0; r < 4; ++r) {
                int row = w * 64 + mt * 16 + quad * 4 + r;
                float v = acc[mt][nt][r] + bias;
                out[row * IN + col] = 1.0f / (1.0f + __expf(-v));
            }
        }
    }
}

extern "C" void kernel_launch(void* const* d_in, const int* in_sizes, int n_in,
                              void* d_out, int out_size, void* d_ws, size_t ws_size,
                              hipStream_t stream) {
    const float* x  = (const float*)d_in[0];
    const float* We = (const float*)d_in[1];
    const float* be = (const float*)d_in[2];
    const float* Wd = (const float*)d_in[3];
    const float* bd = (const float*)d_in[4];
    float* out = (float*)d_out;

    char* ws = (char*)d_ws;
    float* preact          = (float*)ws;                       // 256*1500*4 = 1,536,000 B
    float* rn2             = (float*)(ws + 1536000);           // 1500*4     = 6,000 B
    unsigned short* yenc   = (unsigned short*)(ws + 1544192);  // 256*1536*2 = 786,432 B

    // zero preact + rn2 (ws is poisoned 0xAA before every replay), and the jac slot
    hipMemsetAsync(ws, 0, 1544192, stream);
    hipMemsetAsync(out + 7225344, 0, 4, stream);

    enc_gemm<<<dim3(24, 21), 256, 0, stream>>>(x, We, preact, rn2);
    act_jac<<<dim3(6, 256), 256, 0, stream>>>(preact, be, rn2, yenc, out + 7225344);
    dec_gemm<<<dim3(441, 1), 256, 0, stream>>>(yenc, Wd, bd, out);
}